// Round 5
// baseline (1377.280 us; speedup 1.0000x reference)
//
#include <hip/hip_runtime.h>
#include <hip/hip_bf16.h>
#include <math.h>

#define T_ 1024
#define D_ 256
#define N_ 8192
#define NH_ 4
#define NLAYER_ 6
#define VOCAB_ 256
#define TWO_PI_F 6.283185307179586f
#define INV_TWO_PI_F 0.15915494309189535f

// compact triangular score storage: band ti = 128 rows x (ti+1)*128 cols, row-major
#define SC_HSTR32 294912u    // per-head u32 stride (589824 bf16 / 2)
#define SC_SSTR32 1179648u   // per-split u32 stride (4 heads)
#define SC_SPLIT_BYTES 4718592u
#define SC_NSPLIT 8

typedef __attribute__((ext_vector_type(8))) short short8;
typedef __attribute__((ext_vector_type(4))) float floatx4;
typedef unsigned short ushort_t;

// ---------- async global->LDS 16B ----------
__device__ __forceinline__ void cp16(const void* g, void* l) {
    __builtin_amdgcn_global_load_lds((const __attribute__((address_space(1))) unsigned int*)g,
                                     (__attribute__((address_space(3))) unsigned int*)l,
                                     16, 0, 0);
}

__device__ __forceinline__ float bf2f_raw(unsigned short u) {
    union { unsigned int i; float f; } x;
    x.i = ((unsigned int)u) << 16;
    return x.f;
}
__device__ __forceinline__ unsigned int f2bf_u(float f) {
    union { float f; unsigned int u; } x; x.f = f;
    return (x.u + 0x7fffu + ((x.u >> 16) & 1u)) >> 16;
}
// hardware sin/cos: input in REVOLUTIONS (ph in [0,1)), D = sin/cos(2*pi*ph)
__device__ __forceinline__ float fsin_rev(float ph) {
    float r; asm("v_sin_f32 %0, %1" : "=v"(r) : "v"(ph)); return r;
}
__device__ __forceinline__ float fcos_rev(float ph) {
    float r; asm("v_cos_f32 %0, %1" : "=v"(r) : "v"(ph)); return r;
}

// ---------- block reduce: wave shfl (no sync) + 4-slot LDS combine (2 syncs) ----------
__device__ __forceinline__ float block_sum(float v, float* red) {
    #pragma unroll
    for (int s = 32; s > 0; s >>= 1) v += __shfl_xor(v, s);
    int tid = threadIdx.x;
    if ((tid & 63) == 0) red[tid >> 6] = v;
    __syncthreads();
    float r = red[0] + red[1] + red[2] + red[3];
    __syncthreads();
    return r;
}

// ---------- LN kernels ----------

__global__ void k_embed_ln(const int* __restrict__ idx, const float* __restrict__ ew,
                           float* __restrict__ x, __hip_bfloat16* __restrict__ x_bf) {
    __shared__ float red[4];
    int t = blockIdx.x, d = threadIdx.x;
    float v = ew[idx[t] * D_ + d];
    float mean = block_sum(v, red) * (1.0f / D_);
    float c = v - mean;
    float var = block_sum(c * c, red) * (1.0f / D_);
    float o = c * rsqrtf(var + 1e-5f);
    x[t * D_ + d] = o;
    x_bf[t * D_ + d] = __float2bfloat16(o);
}

// LN over sum of 2 ykv split-K partials -> bf16
__global__ void k_ln_rows(const float* __restrict__ yp, __hip_bfloat16* __restrict__ outb) {
    __shared__ float red[4];
    int r = blockIdx.x, d = threadIdx.x;
    const size_t S = (size_t)NH_ * T_ * D_;
    float v = yp[(size_t)r * D_ + d] + yp[S + (size_t)r * D_ + d];
    float mean = block_sum(v, red) * (1.0f / D_);
    float c = v - mean;
    float var = block_sum(c * c, red) * (1.0f / D_);
    outb[(size_t)r * D_ + d] = __float2bfloat16(c * rsqrtf(var + 1e-5f));
}

// x = ln(x + ln(sum of 32 ymlp partials)); emit fp32 + bf16
__global__ void k_x_update(float* __restrict__ x, const float* __restrict__ ypart,
                           __hip_bfloat16* __restrict__ x_bf) {
    __shared__ float red[4];
    int t = blockIdx.x, d = threadIdx.x;
    float v = 0.0f;
    #pragma unroll
    for (int i = 0; i < 32; i++) v += ypart[(size_t)i * T_ * D_ + t * D_ + d];
    float m1 = block_sum(v, red) * (1.0f / D_);
    float c1 = v - m1;
    float v1 = block_sum(c1 * c1, red) * (1.0f / D_);
    float u = c1 * rsqrtf(v1 + 1e-5f);
    float w = x[t * D_ + d] + u;
    float m2 = block_sum(w, red) * (1.0f / D_);
    float c2 = w - m2;
    float v2 = block_sum(c2 * c2, red) * (1.0f / D_);
    float o = c2 * rsqrtf(v2 + 1e-5f);
    x[t * D_ + d] = o;
    x_bf[t * D_ + d] = __float2bfloat16(o);
}

// ---------- transpose+convert: fp32 [h][R][C] -> bf16 [h][C][R] ----------
__global__ __launch_bounds__(256) void k_tcvt(const float* __restrict__ in,
                                              __hip_bfloat16* __restrict__ out,
                                              int R, int C) {
    int h = blockIdx.z;
    int r0 = blockIdx.y * 32, c0 = blockIdx.x * 32;
    __shared__ float tile[32][33];
    int tx = threadIdx.x & 31, ty = threadIdx.x >> 5;
    const float* inh = in + (size_t)h * R * C;
    __hip_bfloat16* outh = out + (size_t)h * R * C;
    #pragma unroll
    for (int i = 0; i < 4; i++)
        tile[ty + 8 * i][tx] = inh[(size_t)(r0 + ty + 8 * i) * C + c0 + tx];
    __syncthreads();
    #pragma unroll
    for (int i = 0; i < 4; i++)
        outh[(size_t)(c0 + ty + 8 * i) * R + r0 + tx] = __float2bfloat16(tile[tx][ty + 8 * i]);
}

// ---------- core: 128x128 A·B^T bf16 MFMA tile, BK=64, XOR-swizzled LDS ----------
// single-buffer 32KB + __syncthreads: relies on ~4 resident blocks/CU of TLP
// (measured better than 64KB 2-phase dbuf which caps residency at 2 blocks/CU)
__device__ __forceinline__ void gemm128(const ushort_t* __restrict__ A,
                                        const ushort_t* __restrict__ B,
                                        int lda, int ldb, int K,
                                        ushort_t* As, ushort_t* Bs,
                                        floatx4 acc[4][4]) {
    const int tid = threadIdx.x;
    const int lane = tid & 63, wid = tid >> 6;
    const int wm = wid >> 1, wn = wid & 1;
    const int quad = lane >> 4, col = lane & 15;
    int srow[4], scol[4];
    #pragma unroll
    for (int i = 0; i < 4; i++) {
        int s = i * 256 + tid;
        srow[i] = s >> 3;
        scol[i] = (s & 7) ^ (srow[i] & 7);  // XOR swizzle (involutive)
    }
    for (int k0 = 0; k0 < K; k0 += 64) {
        #pragma unroll
        for (int i = 0; i < 4; i++)
            cp16(A + (size_t)srow[i] * lda + k0 + scol[i] * 8,
                 As + (size_t)(i * 256 + wid * 64) * 8);
        #pragma unroll
        for (int i = 0; i < 4; i++)
            cp16(B + (size_t)srow[i] * ldb + k0 + scol[i] * 8,
                 Bs + (size_t)(i * 256 + wid * 64) * 8);
        __syncthreads();
        #pragma unroll
        for (int kk = 0; kk < 2; kk++) {
            short8 af[4], bf[4];
            #pragma unroll
            for (int mi = 0; mi < 4; mi++) {
                int row = wm * 64 + mi * 16 + col;
                int pc = ((kk << 2) + quad) ^ (row & 7);
                af[mi] = *(const short8*)&As[row * 64 + pc * 8];
            }
            #pragma unroll
            for (int ni = 0; ni < 4; ni++) {
                int row = wn * 64 + ni * 16 + col;
                int pc = ((kk << 2) + quad) ^ (row & 7);
                bf[ni] = *(const short8*)&Bs[row * 64 + pc * 8];
            }
            #pragma unroll
            for (int mi = 0; mi < 4; mi++)
                #pragma unroll
                for (int ni = 0; ni < 4; ni++)
                    acc[mi][ni] = __builtin_amdgcn_mfma_f32_16x16x32_bf16(
                        af[mi], bf[ni], acc[mi][ni], 0, 0, 0);
        }
        __syncthreads();
    }
}

#define GEMM_PROLOGUE()                                              \
    __shared__ __align__(16) ushort_t As[128 * 64];                  \
    __shared__ __align__(16) ushort_t Bs[128 * 64];                  \
    floatx4 acc[4][4];                                               \
    _Pragma("unroll") for (int mi = 0; mi < 4; mi++)                 \
        _Pragma("unroll") for (int ni = 0; ni < 4; ni++)             \
            acc[mi][ni] = (floatx4){0.f, 0.f, 0.f, 0.f};             \
    const int lane = threadIdx.x & 63, wid = threadIdx.x >> 6;       \
    const int wm = wid >> 1, wn = wid & 1;                           \
    const int quad = lane >> 4, col = lane & 15;                     \
    const int odd = lane & 1;                                        \
    const int rsel = odd ? 2 : 0, rother = odd ? 0 : 2;

// ---------- scores: qr @ qr^T, triangular 128-tiles, split-K=8, compact bf16 partials ----------
__global__ __launch_bounds__(256) void k_scores_m(const __hip_bfloat16* __restrict__ qr,
                                                  __hip_bfloat16* __restrict__ scp) {
    const int b = blockIdx.x;
    const int slice = b & 31;
    const int h = slice & 3, ks = slice >> 2;
    int i = b >> 5;
    int ti = 0;
    while ((ti + 1) * (ti + 2) / 2 <= i) ti++;
    int si = i - ti * (ti + 1) / 2;
    const int t0 = ti * 128, s0 = si * 128;
    GEMM_PROLOGUE();
    const ushort_t* qh = (const ushort_t*)qr + (size_t)h * T_ * N_ + (size_t)ks * (N_ / 8);
    gemm128(qh + (size_t)t0 * N_, qh + (size_t)s0 * N_, N_, N_, N_ / 8, As, Bs, acc);
    const int W = (ti + 1) * 128;  // band width (= t0+128)
    unsigned int* sch = (unsigned int*)scp + (size_t)ks * SC_SSTR32 + (size_t)h * SC_HSTR32
                        + (size_t)4096 * ti * (ti + 1);  // band offset in u32
    #pragma unroll
    for (int mi = 0; mi < 4; mi++)
        #pragma unroll
        for (int ni = 0; ni < 4; ni++) {
            const int ss = s0 + wn * 64 + ni * 16 + col;
            const int ss_e = ss & ~1;
            const int rowb = wm * 64 + mi * 16 + quad * 4;  // band-local row
            #pragma unroll
            for (int rr = 0; rr < 2; rr++) {
                int tt_o = rowb + rother + rr;
                float send = (ss < t0 + tt_o) ? acc[mi][ni][rother + rr] : 0.0f;
                float recv = __shfl_xor(send, 1);
                int tt = rowb + rsel + rr;
                float mine = (ss < t0 + tt) ? acc[mi][ni][rsel + rr] : 0.0f;
                float lo = odd ? recv : mine, hi = odd ? mine : recv;
                sch[((size_t)tt * W + ss_e) >> 1] = f2bf_u(lo) | (f2bf_u(hi) << 16);
            }
        }
}

// sum the 8 split-K partials into split 0 (compact layout, uint4-wide bf16x2 packed)
// 1152 blocks: head = b & 3; per head 288 blocks x 256 thr x 1 uint4 = 73728 uint4
// = 294912 u32 = entire per-head region, exact cover
__global__ void k_sc_cvt(__hip_bfloat16* __restrict__ scp) {
    const uint4* __restrict__ sp4 = (const uint4*)scp;
    uint4* sp4o = (uint4*)scp;
    int b = blockIdx.x;
    int head = b & 3;
    unsigned int t4 = (unsigned int)(b >> 2) * 256u + threadIdx.x;  // < 73728
    size_t off = (size_t)head * (SC_HSTR32 / 4) + t4;
    float a0 = 0.f, a1 = 0.f, a2 = 0.f, a3 = 0.f, a4 = 0.f, a5 = 0.f, a6 = 0.f, a7 = 0.f;
    #pragma unroll
    for (int s = 0; s < SC_NSPLIT; s++) {
        uint4 w = sp4[off + (size_t)s * (SC_SSTR32 / 4)];
        a0 += bf2f_raw((unsigned short)(w.x & 0xffff));
        a1 += bf2f_raw((unsigned short)(w.x >> 16));
        a2 += bf2f_raw((unsigned short)(w.y & 0xffff));
        a3 += bf2f_raw((unsigned short)(w.y >> 16));
        a4 += bf2f_raw((unsigned short)(w.z & 0xffff));
        a5 += bf2f_raw((unsigned short)(w.z >> 16));
        a6 += bf2f_raw((unsigned short)(w.w & 0xffff));
        a7 += bf2f_raw((unsigned short)(w.w >> 16));
    }
    uint4 o;
    o.x = f2bf_u(a0) | (f2bf_u(a1) << 16);
    o.y = f2bf_u(a2) | (f2bf_u(a3) << 16);
    o.z = f2bf_u(a4) | (f2bf_u(a5) << 16);
    o.w = f2bf_u(a6) | (f2bf_u(a7) << 16);
    sp4o[off] = o;
}

// ---------- proj: A_bf[rows,256] @ Wt[h][n][256]^T, 128-tiles ----------
// RoPE (cos,sin) in-register via raw v_sin/v_cos (revolution input, fract-reduced).
// MODE 0: out1 = qr = rope(relu(acc))
// MODE 1: out1 = xy = invrope(qr) * relu(acc); qr words batch-prefetched into regs
//         (breaks the 32x serialized load->store dependency chain of the naive RMW)
template <int MODE>
__global__ __launch_bounds__(256) void k_proj_m(const __hip_bfloat16* __restrict__ Abf,
                                                const __hip_bfloat16* __restrict__ Wt,
                                                __hip_bfloat16* __restrict__ out1) {
    const int h = blockIdx.z;
    const int t0 = blockIdx.y * 128, n0 = blockIdx.x * 128;
    GEMM_PROLOGUE();
    const ushort_t* Ah = (const ushort_t*)Abf + (MODE ? (size_t)h * T_ * D_ : (size_t)0)
                         + (size_t)t0 * D_;
    const ushort_t* Bh = (const ushort_t*)Wt + (size_t)h * N_ * D_ + (size_t)n0 * D_;
    gemm128(Ah, Bh, D_, D_, D_, As, Bs, acc);
    unsigned int* o1 = (unsigned int*)out1;
    unsigned int xw[4][4][2];
    if (MODE == 1) {
        #pragma unroll
        for (int ni = 0; ni < 4; ni++) {
            const int nn_e = (n0 + wn * 64 + ni * 16 + col) & ~1;
            #pragma unroll
            for (int mi = 0; mi < 4; mi++) {
                const int rowb = t0 + wm * 64 + mi * 16 + quad * 4;
                #pragma unroll
                for (int rr = 0; rr < 2; rr++) {
                    int tt = rowb + rsel + rr;
                    xw[ni][mi][rr] = o1[(((size_t)h * T_ + tt) * (size_t)N_ + nn_e) >> 1];
                }
            }
        }
    }
    #pragma unroll
    for (int ni = 0; ni < 4; ni++) {
        const int nn_e = (n0 + wn * 64 + ni * 16 + col) & ~1;
        const float freq = exp2f((float)(nn_e >> 1) * (-1.0f / 256.0f)) * INV_TWO_PI_F;
        #pragma unroll
        for (int mi = 0; mi < 4; mi++) {
            const int rowb = t0 + wm * 64 + mi * 16 + quad * 4;
            #pragma unroll
            for (int rr = 0; rr < 2; rr++) {
                float send = fmaxf(acc[mi][ni][rother + rr], 0.0f);
                float recv = __shfl_xor(send, 1);
                float mine = fmaxf(acc[mi][ni][rsel + rr], 0.0f);
                float ve = odd ? recv : mine, vo = odd ? mine : recv;
                int tt = rowb + rsel + rr;
                size_t o32 = (((size_t)h * T_ + tt) * (size_t)N_ + nn_e) >> 1;
                float ph = (float)tt * freq;
                ph -= floorf(ph);
                float c = fcos_rev(ph), s = fsin_rev(ph);
                if (MODE == 0) {
                    o1[o32] = f2bf_u(ve * c - vo * s) | (f2bf_u(vo * c + ve * s) << 16);
                } else {
                    unsigned int w = xw[ni][mi][rr];
                    float qe = bf2f_raw((unsigned short)(w & 0xffff));
                    float qo = bf2f_raw((unsigned short)(w >> 16));
                    float xe = qe * c + qo * s;   // inverse rotation (exact: fp32 c,s)
                    float xo = qo * c - qe * s;
                    o1[o32] = f2bf_u(ve * xe) | (f2bf_u(vo * xo) << 16);
                }
            }
        }
    }
}

// ---------- ykv: sc_bf[h] @ xT^T (MFMA), compact band A, K causal-bounded, split-K=2 ----------
__global__ __launch_bounds__(256) void k_ykv_m(const __hip_bfloat16* __restrict__ sc,
                                               const __hip_bfloat16* __restrict__ xT,
                                               float* __restrict__ ykvp) {
    const int b = blockIdx.x;
    const int h = (b >> 1) & 3, ks = b & 1;
    const int r0 = b >> 3;
    const int d0 = (r0 & 1) * 128, t0 = (r0 >> 1) * 128;
    GEMM_PROLOGUE();
    const int W = t0 + 128;       // compact band lda = causal K bound
    const int half = W >> 1;      // multiple of 64
    const int ti = t0 >> 7;
    const ushort_t* Ah = (const ushort_t*)sc + (size_t)h * 589824u
                         + (size_t)8192 * ti * (ti + 1) + (size_t)ks * half;
    const ushort_t* Bh = (const ushort_t*)xT + (size_t)d0 * T_ + (size_t)ks * half;
    gemm128(Ah, Bh, W, T_, half, As, Bs, acc);
    float2* yp = (float2*)(ykvp + (size_t)ks * NH_ * T_ * D_);
    #pragma unroll
    for (int mi = 0; mi < 4; mi++)
        #pragma unroll
        for (int ni = 0; ni < 4; ni++) {
            const int dd_e = (d0 + wn * 64 + ni * 16 + col) & ~1;
            const int rowb = t0 + wm * 64 + mi * 16 + quad * 4;
            #pragma unroll
            for (int rr = 0; rr < 2; rr++) {
                float send = acc[mi][ni][rother + rr];
                float recv = __shfl_xor(send, 1);
                float mine = acc[mi][ni][rsel + rr];
                int tt = rowb + rsel + rr;
                yp[(((size_t)h * T_ + tt) * D_ + dd_e) >> 1] =
                    odd ? make_float2(recv, mine) : make_float2(mine, recv);
            }
        }
}

// ---------- ymlp: xy[h] @ decT[h]^T, split-K=8 into 32 partial buffers ----------
__global__ __launch_bounds__(256) void k_ymlp_m(const __hip_bfloat16* __restrict__ xy,
                                                const __hip_bfloat16* __restrict__ decT,
                                                float* __restrict__ ypart) {
    const int b = blockIdx.x;
    const int slice = b & 31;
    const int ks = slice >> 2, h = slice & 3;
    const int r0 = b >> 5;
    const int d0 = (r0 & 1) * 128, t0 = (r0 >> 1) * 128;
    GEMM_PROLOGUE();
    const ushort_t* Ah = (const ushort_t*)xy + (size_t)h * T_ * N_ + (size_t)t0 * N_ + ks * 1024;
    const ushort_t* Bh = (const ushort_t*)decT + (size_t)h * D_ * N_ + (size_t)d0 * N_ + ks * 1024;
    gemm128(Ah, Bh, N_, N_, 1024, As, Bs, acc);
    float2* yp = (float2*)(ypart + (size_t)slice * T_ * D_);
    #pragma unroll
    for (int mi = 0; mi < 4; mi++)
        #pragma unroll
        for (int ni = 0; ni < 4; ni++) {
            const int dd_e = (d0 + wn * 64 + ni * 16 + col) & ~1;
            const int rowb = t0 + wm * 64 + mi * 16 + quad * 4;
            #pragma unroll
            for (int rr = 0; rr < 2; rr++) {
                float send = acc[mi][ni][rother + rr];
                float recv = __shfl_xor(send, 1);
                float mine = acc[mi][ni][rsel + rr];
                int tt = rowb + rsel + rr;
                yp[((size_t)tt * D_ + dd_e) >> 1] =
                    odd ? make_float2(recv, mine) : make_float2(mine, recv);
            }
        }
}

// ---------- lm_head: x_bf @ lmT^T (MFMA), fp32 out ----------
__global__ __launch_bounds__(256) void k_lmhead_m(const __hip_bfloat16* __restrict__ x_bf,
                                                  const __hip_bfloat16* __restrict__ lmT,
                                                  float* __restrict__ out) {
    const int v0 = blockIdx.x * 128, t0 = blockIdx.y * 128;
    GEMM_PROLOGUE();
    const ushort_t* Ah = (const ushort_t*)x_bf + (size_t)t0 * D_;
    const ushort_t* Bh = (const ushort_t*)lmT + (size_t)v0 * D_;
    gemm128(Ah, Bh, D_, D_, D_, As, Bs, acc);
    float2* op = (float2*)out;
    #pragma unroll
    for (int mi = 0; mi < 4; mi++)
        #pragma unroll
        for (int ni = 0; ni < 4; ni++) {
            const int vv_e = (v0 + wn * 64 + ni * 16 + col) & ~1;
            const int rowb = t0 + wm * 64 + mi * 16 + quad * 4;
            #pragma unroll
            for (int rr = 0; rr < 2; rr++) {
                float send = acc[mi][ni][rother + rr];
                float recv = __shfl_xor(send, 1);
                float mine = acc[mi][ni][rsel + rr];
                int tt = rowb + rsel + rr;
                op[((size_t)tt * VOCAB_ + vv_e) >> 1] =
                    odd ? make_float2(recv, mine) : make_float2(mine, recv);
            }
        }
}

// ---------- launch ----------

extern "C" void kernel_launch(void* const* d_in, const int* in_sizes, int n_in,
                              void* d_out, int out_size, void* d_ws, size_t ws_size,
                              hipStream_t stream) {
    const int* idx = (const int*)d_in[0];
    const float* embed_w = (const float*)d_in[1];
    const float* encoder = (const float*)d_in[2];
    const float* encoder_v = (const float*)d_in[3];
    const float* decoder = (const float*)d_in[4];
    const float* lm_head = (const float*)d_in[5];
    float* out = (float*)d_out;

    char* p = (char*)d_ws;
    auto alloc = [&](size_t bytes) {
        char* q = p;
        p += (bytes + 255) & ~(size_t)255;
        return q;
    };
    float* x = (float*)alloc((size_t)T_ * D_ * 4);
    __hip_bfloat16* x_bf = (__hip_bfloat16*)alloc((size_t)T_ * D_ * 2);
    __hip_bfloat16* xT = (__hip_bfloat16*)alloc((size_t)T_ * D_ * 2);
    __hip_bfloat16* ykv_bf = (__hip_bfloat16*)alloc((size_t)NH_ * T_ * D_ * 2);
    __hip_bfloat16* scp = (__hip_bfloat16*)alloc((size_t)SC_NSPLIT * SC_SPLIT_BYTES);  // 37.75 MB
    __hip_bfloat16* qr = (__hip_bfloat16*)alloc((size_t)NH_ * T_ * N_ * 2);  // qr, then xy in place
    __hip_bfloat16* encT = (__hip_bfloat16*)alloc((size_t)NH_ * N_ * D_ * 2);
    __hip_bfloat16* encvT = (__hip_bfloat16*)alloc((size_t)NH_ * N_ * D_ * 2);
    __hip_bfloat16* decT = (__hip_bfloat16*)alloc((size_t)NH_ * N_ * D_ * 2);
    __hip_bfloat16* lmT = (__hip_bfloat16*)alloc((size_t)VOCAB_ * D_ * 2);
    float* ypart = (float*)alloc((size_t)32 * T_ * D_ * 4);          // 32 MB
    // alias (disjoint lifetime): ykvp in scp splits 1-7 region (free after k_sc_cvt)
    float* ykvp = (float*)((char*)scp + SC_SPLIT_BYTES);

    // one-time: weight transposes
    k_tcvt<<<dim3(N_ / 32, D_ / 32, NH_), 256, 0, stream>>>(encoder, encT, D_, N_);
    k_tcvt<<<dim3(N_ / 32, D_ / 32, NH_), 256, 0, stream>>>(encoder_v, encvT, D_, N_);
    k_tcvt<<<dim3(D_ / 32, N_ / 32, NH_), 256, 0, stream>>>(decoder, decT, N_, D_);
    k_tcvt<<<dim3(VOCAB_ / 32, D_ / 32, 1), 256, 0, stream>>>(lm_head, lmT, D_, VOCAB_);

    k_embed_ln<<<T_, 256, 0, stream>>>(idx, embed_w, x, x_bf);
    for (int l = 0; l < NLAYER_; l++) {
        k_proj_m<0><<<dim3(N_ / 128, T_ / 128, NH_), 256, 0, stream>>>(x_bf, encT, qr);
        k_scores_m<<<36 * 32, 256, 0, stream>>>(qr, scp);
        k_sc_cvt<<<1152, 256, 0, stream>>>(scp);
        k_tcvt<<<dim3(D_ / 32, T_ / 32, 1), 256, 0, stream>>>(x, xT, T_, D_);
        k_ykv_m<<<16 * 8, 256, 0, stream>>>(scp, xT, ykvp);
        k_ln_rows<<<NH_ * T_, 256, 0, stream>>>(ykvp, ykv_bf);
        k_proj_m<1><<<dim3(N_ / 128, T_ / 128, NH_), 256, 0, stream>>>(ykv_bf, encvT, qr /*xy*/);
        k_ymlp_m<<<16 * 32, 256, 0, stream>>>(qr, decT, ypart);
        k_x_update<<<T_, 256, 0, stream>>>(x, ypart, x_bf);
    }
    k_lmhead_m<<<dim3(VOCAB_ / 128, T_ / 128), 256, 0, stream>>>(x_bf, lmT, out);
}

// Round 6
// 1305.978 us; speedup vs baseline: 1.0546x; 1.0546x over previous
//
#include <hip/hip_runtime.h>
#include <hip/hip_bf16.h>
#include <math.h>

#define T_ 1024
#define D_ 256
#define N_ 8192
#define NH_ 4
#define NLAYER_ 6
#define VOCAB_ 256
#define TWO_PI_F 6.283185307179586f
#define INV_TWO_PI_F 0.15915494309189535f

// compact triangular score storage: band ti = 128 rows x (ti+1)*128 cols, row-major
#define SC_HSTR32 294912u    // per-head u32 stride (589824 bf16 / 2)
#define SC_SSTR32 1179648u   // per-split u32 stride (4 heads)
#define SC_SPLIT_BYTES 4718592u
#define SC_NSPLIT 8

typedef __attribute__((ext_vector_type(8))) short short8;
typedef __attribute__((ext_vector_type(4))) float floatx4;
typedef unsigned short ushort_t;

// ---------- async global->LDS 16B ----------
__device__ __forceinline__ void cp16(const void* g, void* l) {
    __builtin_amdgcn_global_load_lds((const __attribute__((address_space(1))) unsigned int*)g,
                                     (__attribute__((address_space(3))) unsigned int*)l,
                                     16, 0, 0);
}

__device__ __forceinline__ float bf2f_raw(unsigned short u) {
    union { unsigned int i; float f; } x;
    x.i = ((unsigned int)u) << 16;
    return x.f;
}
__device__ __forceinline__ unsigned int f2bf_u(float f) {
    union { float f; unsigned int u; } x; x.f = f;
    return (x.u + 0x7fffu + ((x.u >> 16) & 1u)) >> 16;
}
// hardware sin/cos: input in REVOLUTIONS (ph in [0,1)), D = sin/cos(2*pi*ph)
__device__ __forceinline__ float fsin_rev(float ph) {
    float r; asm("v_sin_f32 %0, %1" : "=v"(r) : "v"(ph)); return r;
}
__device__ __forceinline__ float fcos_rev(float ph) {
    float r; asm("v_cos_f32 %0, %1" : "=v"(r) : "v"(ph)); return r;
}

// ---------- block reduce: wave shfl (no sync) + 4-slot LDS combine (2 syncs) ----------
__device__ __forceinline__ float block_sum(float v, float* red) {
    #pragma unroll
    for (int s = 32; s > 0; s >>= 1) v += __shfl_xor(v, s);
    int tid = threadIdx.x;
    if ((tid & 63) == 0) red[tid >> 6] = v;
    __syncthreads();
    float r = red[0] + red[1] + red[2] + red[3];
    __syncthreads();
    return r;
}

// ---------- LN kernels ----------

__global__ void k_embed_ln(const int* __restrict__ idx, const float* __restrict__ ew,
                           float* __restrict__ x, __hip_bfloat16* __restrict__ x_bf) {
    __shared__ float red[4];
    int t = blockIdx.x, d = threadIdx.x;
    float v = ew[idx[t] * D_ + d];
    float mean = block_sum(v, red) * (1.0f / D_);
    float c = v - mean;
    float var = block_sum(c * c, red) * (1.0f / D_);
    float o = c * rsqrtf(var + 1e-5f);
    x[t * D_ + d] = o;
    x_bf[t * D_ + d] = __float2bfloat16(o);
}

// LN over sum of 2 ykv split-K partials -> bf16
__global__ void k_ln_rows(const float* __restrict__ yp, __hip_bfloat16* __restrict__ outb) {
    __shared__ float red[4];
    int r = blockIdx.x, d = threadIdx.x;
    const size_t S = (size_t)NH_ * T_ * D_;
    float v = yp[(size_t)r * D_ + d] + yp[S + (size_t)r * D_ + d];
    float mean = block_sum(v, red) * (1.0f / D_);
    float c = v - mean;
    float var = block_sum(c * c, red) * (1.0f / D_);
    outb[(size_t)r * D_ + d] = __float2bfloat16(c * rsqrtf(var + 1e-5f));
}

// x = ln(x + ln(sum of 32 ymlp partials)); emit fp32 + bf16
__global__ void k_x_update(float* __restrict__ x, const float* __restrict__ ypart,
                           __hip_bfloat16* __restrict__ x_bf) {
    __shared__ float red[4];
    int t = blockIdx.x, d = threadIdx.x;
    float v = 0.0f;
    #pragma unroll
    for (int i = 0; i < 32; i++) v += ypart[(size_t)i * T_ * D_ + t * D_ + d];
    float m1 = block_sum(v, red) * (1.0f / D_);
    float c1 = v - m1;
    float v1 = block_sum(c1 * c1, red) * (1.0f / D_);
    float u = c1 * rsqrtf(v1 + 1e-5f);
    float w = x[t * D_ + d] + u;
    float m2 = block_sum(w, red) * (1.0f / D_);
    float c2 = w - m2;
    float v2 = block_sum(c2 * c2, red) * (1.0f / D_);
    float o = c2 * rsqrtf(v2 + 1e-5f);
    x[t * D_ + d] = o;
    x_bf[t * D_ + d] = __float2bfloat16(o);
}

// ---------- transpose+convert: fp32 [h][R][C] -> bf16 [h][C][R] ----------
__global__ __launch_bounds__(256) void k_tcvt(const float* __restrict__ in,
                                              __hip_bfloat16* __restrict__ out,
                                              int R, int C) {
    int h = blockIdx.z;
    int r0 = blockIdx.y * 32, c0 = blockIdx.x * 32;
    __shared__ float tile[32][33];
    int tx = threadIdx.x & 31, ty = threadIdx.x >> 5;
    const float* inh = in + (size_t)h * R * C;
    __hip_bfloat16* outh = out + (size_t)h * R * C;
    #pragma unroll
    for (int i = 0; i < 4; i++)
        tile[ty + 8 * i][tx] = inh[(size_t)(r0 + ty + 8 * i) * C + c0 + tx];
    __syncthreads();
    #pragma unroll
    for (int i = 0; i < 4; i++)
        outh[(size_t)(c0 + ty + 8 * i) * R + r0 + tx] = __float2bfloat16(tile[tx][ty + 8 * i]);
}

// ---------- core: 128x128 A·B^T bf16 MFMA tile, BK=64, XOR-swizzled LDS ----------
// single-buffer 32KB + __syncthreads: relies on ~4 resident blocks/CU of TLP
__device__ __forceinline__ void gemm128(const ushort_t* __restrict__ A,
                                        const ushort_t* __restrict__ B,
                                        int lda, int ldb, int K,
                                        ushort_t* As, ushort_t* Bs,
                                        floatx4 acc[4][4]) {
    const int tid = threadIdx.x;
    const int lane = tid & 63, wid = tid >> 6;
    const int wm = wid >> 1, wn = wid & 1;
    const int quad = lane >> 4, col = lane & 15;
    int srow[4], scol[4];
    #pragma unroll
    for (int i = 0; i < 4; i++) {
        int s = i * 256 + tid;
        srow[i] = s >> 3;
        scol[i] = (s & 7) ^ (srow[i] & 7);  // XOR swizzle (involutive)
    }
    for (int k0 = 0; k0 < K; k0 += 64) {
        #pragma unroll
        for (int i = 0; i < 4; i++)
            cp16(A + (size_t)srow[i] * lda + k0 + scol[i] * 8,
                 As + (size_t)(i * 256 + wid * 64) * 8);
        #pragma unroll
        for (int i = 0; i < 4; i++)
            cp16(B + (size_t)srow[i] * ldb + k0 + scol[i] * 8,
                 Bs + (size_t)(i * 256 + wid * 64) * 8);
        __syncthreads();
        #pragma unroll
        for (int kk = 0; kk < 2; kk++) {
            short8 af[4], bf[4];
            #pragma unroll
            for (int mi = 0; mi < 4; mi++) {
                int row = wm * 64 + mi * 16 + col;
                int pc = ((kk << 2) + quad) ^ (row & 7);
                af[mi] = *(const short8*)&As[row * 64 + pc * 8];
            }
            #pragma unroll
            for (int ni = 0; ni < 4; ni++) {
                int row = wn * 64 + ni * 16 + col;
                int pc = ((kk << 2) + quad) ^ (row & 7);
                bf[ni] = *(const short8*)&Bs[row * 64 + pc * 8];
            }
            #pragma unroll
            for (int mi = 0; mi < 4; mi++)
                #pragma unroll
                for (int ni = 0; ni < 4; ni++)
                    acc[mi][ni] = __builtin_amdgcn_mfma_f32_16x16x32_bf16(
                        af[mi], bf[ni], acc[mi][ni], 0, 0, 0);
        }
        __syncthreads();
    }
}

// smem is a single 32KB block: As/Bs during gemm; 128x128 bf16 output tile in epilogue
#define GEMM_PROLOGUE()                                              \
    __shared__ __align__(16) ushort_t smem[2 * 128 * 64];            \
    ushort_t* As = smem;                                             \
    ushort_t* Bs = smem + 128 * 64;                                  \
    floatx4 acc[4][4];                                               \
    _Pragma("unroll") for (int mi = 0; mi < 4; mi++)                 \
        _Pragma("unroll") for (int ni = 0; ni < 4; ni++)             \
            acc[mi][ni] = (floatx4){0.f, 0.f, 0.f, 0.f};             \
    const int lane = threadIdx.x & 63, wid = threadIdx.x >> 6;       \
    const int wm = wid >> 1, wn = wid & 1;                           \
    const int quad = lane >> 4, col = lane & 15;                     \
    const int odd = lane & 1;                                        \
    const int rsel = odd ? 2 : 0, rother = odd ? 0 : 2;

// ---------- scores: qr @ qr^T, triangular 128-tiles, split-K=8, compact bf16 partials ----------
// epilogue: pack tile into LDS (XOR bank-swizzle), then coalesced uint4 stores
__global__ __launch_bounds__(256) void k_scores_m(const __hip_bfloat16* __restrict__ qr,
                                                  __hip_bfloat16* __restrict__ scp) {
    const int b = blockIdx.x;
    const int slice = b & 31;
    const int h = slice & 3, ks = slice >> 2;
    int i = b >> 5;
    int ti = 0;
    while ((ti + 1) * (ti + 2) / 2 <= i) ti++;
    int si = i - ti * (ti + 1) / 2;
    const int t0 = ti * 128, s0 = si * 128;
    GEMM_PROLOGUE();
    const ushort_t* qh = (const ushort_t*)qr + (size_t)h * T_ * N_ + (size_t)ks * (N_ / 8);
    gemm128(qh + (size_t)t0 * N_, qh + (size_t)s0 * N_, N_, N_, N_ / 8, As, Bs, acc);
    unsigned int* osm = (unsigned int*)smem;
    #pragma unroll
    for (int mi = 0; mi < 4; mi++)
        #pragma unroll
        for (int ni = 0; ni < 4; ni++) {
            const int ss = s0 + wn * 64 + ni * 16 + col;       // global col
            const int cc = (wn * 64 + ni * 16 + col) >> 1;     // local u32 col
            const int rowb = wm * 64 + mi * 16 + quad * 4;     // band-local row
            #pragma unroll
            for (int rr = 0; rr < 2; rr++) {
                int tt_o = rowb + rother + rr;
                float send = (ss < t0 + tt_o) ? acc[mi][ni][rother + rr] : 0.0f;
                float recv = __shfl_xor(send, 1);
                int tt = rowb + rsel + rr;
                float mine = (ss < t0 + tt) ? acc[mi][ni][rsel + rr] : 0.0f;
                float lo = odd ? recv : mine, hi = odd ? mine : recv;
                osm[tt * 64 + (cc ^ ((tt & 7) << 3))] = f2bf_u(lo) | (f2bf_u(hi) << 16);
            }
        }
    __syncthreads();
    const unsigned int Wu = (unsigned int)(ti + 1) * 64;  // band u32 row stride
    unsigned int* bb = (unsigned int*)scp + (size_t)ks * SC_SSTR32 + (size_t)h * SC_HSTR32
                       + (size_t)4096 * ti * (ti + 1);
    uint4* sc4 = (uint4*)bb;
    const uint4* osm4 = (const uint4*)osm;
    #pragma unroll
    for (int i2 = 0; i2 < 8; i2++) {
        int idx = i2 * 256 + threadIdx.x;
        int row = idx >> 4, c4 = idx & 15;
        uint4 w = osm4[row * 16 + (c4 ^ ((row & 7) << 1))];
        sc4[((size_t)row * Wu + (size_t)si * 64) / 4 + c4] = w;
    }
}

// sum the 8 split-K partials into split 0 (compact layout, uint4-wide bf16x2 packed)
__global__ void k_sc_cvt(__hip_bfloat16* __restrict__ scp) {
    const uint4* __restrict__ sp4 = (const uint4*)scp;
    uint4* sp4o = (uint4*)scp;
    int b = blockIdx.x;
    int head = b & 3;
    unsigned int t4 = (unsigned int)(b >> 2) * 256u + threadIdx.x;  // < 73728
    size_t off = (size_t)head * (SC_HSTR32 / 4) + t4;
    float a0 = 0.f, a1 = 0.f, a2 = 0.f, a3 = 0.f, a4 = 0.f, a5 = 0.f, a6 = 0.f, a7 = 0.f;
    #pragma unroll
    for (int s = 0; s < SC_NSPLIT; s++) {
        uint4 w = sp4[off + (size_t)s * (SC_SSTR32 / 4)];
        a0 += bf2f_raw((unsigned short)(w.x & 0xffff));
        a1 += bf2f_raw((unsigned short)(w.x >> 16));
        a2 += bf2f_raw((unsigned short)(w.y & 0xffff));
        a3 += bf2f_raw((unsigned short)(w.y >> 16));
        a4 += bf2f_raw((unsigned short)(w.z & 0xffff));
        a5 += bf2f_raw((unsigned short)(w.z >> 16));
        a6 += bf2f_raw((unsigned short)(w.w & 0xffff));
        a7 += bf2f_raw((unsigned short)(w.w >> 16));
    }
    uint4 o;
    o.x = f2bf_u(a0) | (f2bf_u(a1) << 16);
    o.y = f2bf_u(a2) | (f2bf_u(a3) << 16);
    o.z = f2bf_u(a4) | (f2bf_u(a5) << 16);
    o.w = f2bf_u(a6) | (f2bf_u(a7) << 16);
    sp4o[off] = o;
}

// ---------- proj: A_bf[rows,256] @ Wt[h][n][256]^T, 128-tiles ----------
// RoPE in-register via raw v_sin/v_cos. LDS-coalesced epilogue:
// MODE 0: out1 = qr = rope(relu(acc))
// MODE 1: out1 = xy = invrope(qr) * relu(acc); qr tile loaded via global_load_lds
//         (linear LDS dest + inverse-swizzled global src), gathered, overwritten
template <int MODE>
__global__ __launch_bounds__(256) void k_proj_m(const __hip_bfloat16* __restrict__ Abf,
                                                const __hip_bfloat16* __restrict__ Wt,
                                                __hip_bfloat16* __restrict__ out1) {
    const int h = blockIdx.z;
    const int t0 = blockIdx.y * 128, n0 = blockIdx.x * 128;
    GEMM_PROLOGUE();
    const ushort_t* Ah = (const ushort_t*)Abf + (MODE ? (size_t)h * T_ * D_ : (size_t)0)
                         + (size_t)t0 * D_;
    const ushort_t* Bh = (const ushort_t*)Wt + (size_t)h * N_ * D_ + (size_t)n0 * D_;
    gemm128(Ah, Bh, D_, D_, D_, As, Bs, acc);
    unsigned int* osm = (unsigned int*)smem;
    unsigned int xw[4][4][2];
    if (MODE == 1) {
        // coalesced qr tile -> LDS: linear dest, swizzled per-lane global source
        const unsigned int* q32 = (const unsigned int*)out1;
        const int c4p = lane & 15, rl4 = lane >> 4;
        #pragma unroll
        for (int i = 0; i < 8; i++) {
            int chunk = i * 4 + wid;          // wave-uniform
            int row_l = chunk * 4 + rl4;      // 0..127
            size_t g32 = (size_t)(h * T_ + t0 + row_l) * (size_t)(N_ / 2) + (size_t)(n0 >> 1)
                         + (size_t)(4 * (c4p ^ ((row_l & 7) << 1)));
            cp16(q32 + g32, osm + chunk * 256);
        }
        __syncthreads();
        #pragma unroll
        for (int ni = 0; ni < 4; ni++) {
            const int cc = (wn * 64 + ni * 16 + col) >> 1;
            #pragma unroll
            for (int mi = 0; mi < 4; mi++) {
                const int rowb = wm * 64 + mi * 16 + quad * 4;
                #pragma unroll
                for (int rr = 0; rr < 2; rr++) {
                    int tt = rowb + rsel + rr;
                    xw[ni][mi][rr] = osm[tt * 64 + (cc ^ ((tt & 7) << 3))];
                }
            }
        }
        __syncthreads();  // all gathers done before overwrite
    }
    #pragma unroll
    for (int ni = 0; ni < 4; ni++) {
        const int cc = (wn * 64 + ni * 16 + col) >> 1;
        const int nn_e = (n0 + wn * 64 + ni * 16 + col) & ~1;
        const float freq = exp2f((float)(nn_e >> 1) * (-1.0f / 256.0f)) * INV_TWO_PI_F;
        #pragma unroll
        for (int mi = 0; mi < 4; mi++) {
            const int rowb = wm * 64 + mi * 16 + quad * 4;  // local row base
            #pragma unroll
            for (int rr = 0; rr < 2; rr++) {
                float send = fmaxf(acc[mi][ni][rother + rr], 0.0f);
                float recv = __shfl_xor(send, 1);
                float mine = fmaxf(acc[mi][ni][rsel + rr], 0.0f);
                float ve = odd ? recv : mine, vo = odd ? mine : recv;
                int tt = rowb + rsel + rr;
                float ph = (float)(t0 + tt) * freq;
                ph -= floorf(ph);
                float c = fcos_rev(ph), s = fsin_rev(ph);
                unsigned int pk;
                if (MODE == 0) {
                    pk = f2bf_u(ve * c - vo * s) | (f2bf_u(vo * c + ve * s) << 16);
                } else {
                    unsigned int w = xw[ni][mi][rr];
                    float qe = bf2f_raw((unsigned short)(w & 0xffff));
                    float qo = bf2f_raw((unsigned short)(w >> 16));
                    pk = f2bf_u(ve * (qe * c + qo * s)) | (f2bf_u(vo * (qo * c - qe * s)) << 16);
                }
                osm[tt * 64 + (cc ^ ((tt & 7) << 3))] = pk;
            }
        }
    }
    __syncthreads();
    uint4* o4 = (uint4*)out1;
    const uint4* osm4 = (const uint4*)osm;
    #pragma unroll
    for (int i2 = 0; i2 < 8; i2++) {
        int idx = i2 * 256 + threadIdx.x;
        int row = idx >> 4, c4 = idx & 15;
        uint4 w = osm4[row * 16 + (c4 ^ ((row & 7) << 1))];
        o4[(size_t)(h * T_ + t0 + row) * (size_t)(N_ / 8) + (size_t)(n0 >> 3) + c4] = w;
    }
}

// ---------- ykv: sc_bf[h] @ xT^T (MFMA), compact band A, K causal-bounded, split-K=2 ----------
__global__ __launch_bounds__(256) void k_ykv_m(const __hip_bfloat16* __restrict__ sc,
                                               const __hip_bfloat16* __restrict__ xT,
                                               float* __restrict__ ykvp) {
    const int b = blockIdx.x;
    const int h = (b >> 1) & 3, ks = b & 1;
    const int r0 = b >> 3;
    const int d0 = (r0 & 1) * 128, t0 = (r0 >> 1) * 128;
    GEMM_PROLOGUE();
    const int W = t0 + 128;       // compact band lda = causal K bound
    const int half = W >> 1;      // multiple of 64
    const int ti = t0 >> 7;
    const ushort_t* Ah = (const ushort_t*)sc + (size_t)h * 589824u
                         + (size_t)8192 * ti * (ti + 1) + (size_t)ks * half;
    const ushort_t* Bh = (const ushort_t*)xT + (size_t)d0 * T_ + (size_t)ks * half;
    gemm128(Ah, Bh, W, T_, half, As, Bs, acc);
    float2* yp = (float2*)(ykvp + (size_t)ks * NH_ * T_ * D_);
    #pragma unroll
    for (int mi = 0; mi < 4; mi++)
        #pragma unroll
        for (int ni = 0; ni < 4; ni++) {
            const int dd_e = (d0 + wn * 64 + ni * 16 + col) & ~1;
            const int rowb = t0 + wm * 64 + mi * 16 + quad * 4;
            #pragma unroll
            for (int rr = 0; rr < 2; rr++) {
                float send = acc[mi][ni][rother + rr];
                float recv = __shfl_xor(send, 1);
                float mine = acc[mi][ni][rsel + rr];
                int tt = rowb + rsel + rr;
                yp[(((size_t)h * T_ + tt) * D_ + dd_e) >> 1] =
                    odd ? make_float2(recv, mine) : make_float2(mine, recv);
            }
        }
}

// ---------- ymlp: xy[h] @ decT[h]^T, split-K=8 into 32 partial buffers ----------
__global__ __launch_bounds__(256) void k_ymlp_m(const __hip_bfloat16* __restrict__ xy,
                                                const __hip_bfloat16* __restrict__ decT,
                                                float* __restrict__ ypart) {
    const int b = blockIdx.x;
    const int slice = b & 31;
    const int ks = slice >> 2, h = slice & 3;
    const int r0 = b >> 5;
    const int d0 = (r0 & 1) * 128, t0 = (r0 >> 1) * 128;
    GEMM_PROLOGUE();
    const ushort_t* Ah = (const ushort_t*)xy + (size_t)h * T_ * N_ + (size_t)t0 * N_ + ks * 1024;
    const ushort_t* Bh = (const ushort_t*)decT + (size_t)h * D_ * N_ + (size_t)d0 * N_ + ks * 1024;
    gemm128(Ah, Bh, N_, N_, 1024, As, Bs, acc);
    float2* yp = (float2*)(ypart + (size_t)slice * T_ * D_);
    #pragma unroll
    for (int mi = 0; mi < 4; mi++)
        #pragma unroll
        for (int ni = 0; ni < 4; ni++) {
            const int dd_e = (d0 + wn * 64 + ni * 16 + col) & ~1;
            const int rowb = t0 + wm * 64 + mi * 16 + quad * 4;
            #pragma unroll
            for (int rr = 0; rr < 2; rr++) {
                float send = acc[mi][ni][rother + rr];
                float recv = __shfl_xor(send, 1);
                float mine = acc[mi][ni][rsel + rr];
                int tt = rowb + rsel + rr;
                yp[((size_t)tt * D_ + dd_e) >> 1] =
                    odd ? make_float2(recv, mine) : make_float2(mine, recv);
            }
        }
}

// ---------- lm_head: x_bf @ lmT^T (MFMA), fp32 out ----------
__global__ __launch_bounds__(256) void k_lmhead_m(const __hip_bfloat16* __restrict__ x_bf,
                                                  const __hip_bfloat16* __restrict__ lmT,
                                                  float* __restrict__ out) {
    const int v0 = blockIdx.x * 128, t0 = blockIdx.y * 128;
    GEMM_PROLOGUE();
    const ushort_t* Ah = (const ushort_t*)x_bf + (size_t)t0 * D_;
    const ushort_t* Bh = (const ushort_t*)lmT + (size_t)v0 * D_;
    gemm128(Ah, Bh, D_, D_, D_, As, Bs, acc);
    float2* op = (float2*)out;
    #pragma unroll
    for (int mi = 0; mi < 4; mi++)
        #pragma unroll
        for (int ni = 0; ni < 4; ni++) {
            const int vv_e = (v0 + wn * 64 + ni * 16 + col) & ~1;
            const int rowb = t0 + wm * 64 + mi * 16 + quad * 4;
            #pragma unroll
            for (int rr = 0; rr < 2; rr++) {
                float send = acc[mi][ni][rother + rr];
                float recv = __shfl_xor(send, 1);
                float mine = acc[mi][ni][rsel + rr];
                int tt = rowb + rsel + rr;
                op[((size_t)tt * VOCAB_ + vv_e) >> 1] =
                    odd ? make_float2(recv, mine) : make_float2(mine, recv);
            }
        }
}

// ---------- launch ----------

extern "C" void kernel_launch(void* const* d_in, const int* in_sizes, int n_in,
                              void* d_out, int out_size, void* d_ws, size_t ws_size,
                              hipStream_t stream) {
    const int* idx = (const int*)d_in[0];
    const float* embed_w = (const float*)d_in[1];
    const float* encoder = (const float*)d_in[2];
    const float* encoder_v = (const float*)d_in[3];
    const float* decoder = (const float*)d_in[4];
    const float* lm_head = (const float*)d_in[5];
    float* out = (float*)d_out;

    char* p = (char*)d_ws;
    auto alloc = [&](size_t bytes) {
        char* q = p;
        p += (bytes + 255) & ~(size_t)255;
        return q;
    };
    float* x = (float*)alloc((size_t)T_ * D_ * 4);
    __hip_bfloat16* x_bf = (__hip_bfloat16*)alloc((size_t)T_ * D_ * 2);
    __hip_bfloat16* xT = (__hip_bfloat16*)alloc((size_t)T_ * D_ * 2);
    __hip_bfloat16* ykv_bf = (__hip_bfloat16*)alloc((size_t)NH_ * T_ * D_ * 2);
    __hip_bfloat16* scp = (__hip_bfloat16*)alloc((size_t)SC_NSPLIT * SC_SPLIT_BYTES);  // 37.75 MB
    __hip_bfloat16* qr = (__hip_bfloat16*)alloc((size_t)NH_ * T_ * N_ * 2);  // qr, then xy in place
    __hip_bfloat16* encT = (__hip_bfloat16*)alloc((size_t)NH_ * N_ * D_ * 2);
    __hip_bfloat16* encvT = (__hip_bfloat16*)alloc((size_t)NH_ * N_ * D_ * 2);
    __hip_bfloat16* decT = (__hip_bfloat16*)alloc((size_t)NH_ * N_ * D_ * 2);
    __hip_bfloat16* lmT = (__hip_bfloat16*)alloc((size_t)VOCAB_ * D_ * 2);
    float* ypart = (float*)alloc((size_t)32 * T_ * D_ * 4);          // 32 MB
    // alias (disjoint lifetime): ykvp in scp splits 1-7 region (free after k_sc_cvt)
    float* ykvp = (float*)((char*)scp + SC_SPLIT_BYTES);

    // one-time: weight transposes
    k_tcvt<<<dim3(N_ / 32, D_ / 32, NH_), 256, 0, stream>>>(encoder, encT, D_, N_);
    k_tcvt<<<dim3(N_ / 32, D_ / 32, NH_), 256, 0, stream>>>(encoder_v, encvT, D_, N_);
    k_tcvt<<<dim3(D_ / 32, N_ / 32, NH_), 256, 0, stream>>>(decoder, decT, N_, D_);
    k_tcvt<<<dim3(VOCAB_ / 32, D_ / 32, 1), 256, 0, stream>>>(lm_head, lmT, D_, VOCAB_);

    k_embed_ln<<<T_, 256, 0, stream>>>(idx, embed_w, x, x_bf);
    for (int l = 0; l < NLAYER_; l++) {
        k_proj_m<0><<<dim3(N_ / 128, T_ / 128, NH_), 256, 0, stream>>>(x_bf, encT, qr);
        k_scores_m<<<36 * 32, 256, 0, stream>>>(qr, scp);
        k_sc_cvt<<<1152, 256, 0, stream>>>(scp);
        k_tcvt<<<dim3(D_ / 32, T_ / 32, 1), 256, 0, stream>>>(x, xT, T_, D_);
        k_ykv_m<<<16 * 8, 256, 0, stream>>>(scp, xT, ykvp);
        k_ln_rows<<<NH_ * T_, 256, 0, stream>>>(ykvp, ykv_bf);
        k_proj_m<1><<<dim3(N_ / 128, T_ / 128, NH_), 256, 0, stream>>>(ykv_bf, encvT, qr /*xy*/);
        k_ymlp_m<<<16 * 32, 256, 0, stream>>>(qr, decT, ypart);
        k_x_update<<<T_, 256, 0, stream>>>(x, ypart, x_bf);
    }
    k_lmhead_m<<<dim3(VOCAB_ / 128, T_ / 128), 256, 0, stream>>>(x_bf, lmT, out);
}